// Round 17
// baseline (161.054 us; speedup 1.0000x reference)
//
#include <hip/hip_runtime.h>

#define TSTEPS 2048
#define BATCH  4096
#define HID    4
#define STRIDE (BATCH*HID)    // 16384 floats per timestep slab
#define CH     32             // timesteps per chunk (barrier period)
#define NCHUNK (TSTEPS/CH)    // 64 source chunks
#define NPH    69             // >= NCHUNK+4, = 3*23 for static slot rotation

// Broadcast component k (0..3) to all 4 lanes of each quad via DPP quad_perm.
#define QB(v,k) __int_as_float(__builtin_amdgcn_update_dpp( \
    0, __float_as_int(v), (k)*0x55, 0xF, 0xF, true))

__device__ __forceinline__ float fast_exp2(float x) {
#if __has_builtin(__builtin_amdgcn_exp2f)
  return __builtin_amdgcn_exp2f(x);
#else
  return exp2f(x);
#endif
}
__device__ __forceinline__ float fast_rcp(float x) {
#if __has_builtin(__builtin_amdgcn_rcpf)
  return __builtin_amdgcn_rcpf(x);
#else
  return 1.0f / x;
#endif
}

// Direct global->LDS 4B load (wave-uniform LDS base + lane*4).
__device__ __forceinline__ void xload(float* ldst, const float* gsrc) {
  __builtin_amdgcn_global_load_lds(
      (const __attribute__((address_space(1))) void*)gsrc,
      (__attribute__((address_space(3))) void*)ldst, 4, 0, 0);
}

// 8-wave dual-group producer/consumer pipeline (r15 structure x2 per block).
// Two independent 4-wave groups per 512-thread block; each SIMD hosts two
// same-role waves -> group B's issue fills group A's chain stalls (r14 probe:
// chain = 69 cyc/step; single-group r15 = 135 cyc/step, issue-starved SIMDs).
//   role 0: x staging + layer0 ai -> iface[g][0]
//   role 1: tail L0 + ai L1 -> iface[g][1]   (DPP-shared, see below)
//   role 2: tail L1 + ai L2 -> iface[g][2]
//   role 3: tail L2 + Y store
// Recurrence on r = 1/(1+exp2(a)), h = 1-2r folded into ALL weights:
//   chain: a = av[u] + whp.quad(r), whp = -2K*Whh
//   ai-production consumes quad(r) too: wip = -2*K*Wih(next),
//   cbn = K*(b(next) + Whh(next).1 + Wih(next).1)  -> the SAME 4 DPPs feed
//   chain(u+1) and ai(u) (ai emitted one step delayed; epilogue emits ai(31)).
// Protocol per r9/r15: double-buffered ifaces (par = m&1), ONE raw s_barrier
// per phase, lgkmcnt(0) drained before it, vmcnt counted (32), never drained
// in-loop. Wave of role l at phase p handles chunk m = p - l.
__global__ __launch_bounds__(512) void rnn_pipe8(
    const float* __restrict__ X,    // (T, B, H)
    const float* __restrict__ H0,   // (L, B, H)
    const float* __restrict__ Wih,  // (L, H, H)
    const float* __restrict__ Whh,  // (L, H, H)
    const float* __restrict__ bih,  // (L, H)
    const float* __restrict__ bhh,  // (L, H)
    float* __restrict__ Y)          // (T, B, H)
{
  const int lane = threadIdx.x & 63;
  const int w    = threadIdx.x >> 6;            // 0..7
  const int role = w & 3;                       // 0 producer, 1..3 layers
  const int grp  = w >> 2;                      // 0,1
  const int g    = blockIdx.x * 128 + grp * 64 + lane;
  const int j    = g & 3;
  const float K  = 2.8853900817779268f;         // 2*log2(e)

  __shared__ float iface[2][3][2][CH][64];      // 96 KB [grp][l][par][u][lane]
  __shared__ float xbuf[2][3][CH][64];          // 48 KB [grp][slot][u][lane]

  // Per-role weights.
  float whp[HID], wip[HID], cbn = 0.0f, r = 0.0f;
  {
    if (role >= 1) {                            // tail of layer role-1
      const int Lt = role - 1;
#pragma unroll
      for (int k = 0; k < HID; ++k)
        whp[k] = -2.0f * K * Whh[(Lt*HID + j)*HID + k];
      r = 0.5f * (1.0f - H0[Lt*STRIDE + g]);    // h = 1 - 2r
    }
    if (role == 0) {                            // layer0 ai from raw x
      const int Ln = 0;
      float wsum = 0.0f;
#pragma unroll
      for (int k = 0; k < HID; ++k) {
        wip[k] = K * Wih[(Ln*HID + j)*HID + k];
        wsum  += Whh[(Ln*HID + j)*HID + k];
      }
      cbn = K * (bih[Ln*HID + j] + bhh[Ln*HID + j] + wsum);
    } else if (role <= 2) {                     // next-layer ai from quad(r)
      const int Ln = role;
      float wsum = 0.0f;
#pragma unroll
      for (int k = 0; k < HID; ++k) {
        float wik = Wih[(Ln*HID + j)*HID + k];
        wip[k] = -2.0f * K * wik;
        wsum  += Whh[(Ln*HID + j)*HID + k] + wik;
      }
      cbn = K * (bih[Ln*HID + j] + bhh[Ln*HID + j] + wsum);
    }
  }

  const float* __restrict__ xp = X + g;

  // Prime the x pipeline: chunks 0,1 -> slots 0,1 (64 outstanding loads).
  if (role == 0) {
    __builtin_amdgcn_sched_barrier(0);
    asm volatile("s_waitcnt vmcnt(0)" ::: "memory");  // clean vmcnt baseline
#pragma unroll
    for (int u = 0; u < CH; ++u)
      xload(&xbuf[grp][0][u][0], xp + (size_t)(0*CH + u) * STRIDE);
#pragma unroll
    for (int u = 0; u < CH; ++u)
      xload(&xbuf[grp][1][u][0], xp + (size_t)(1*CH + u) * STRIDE);
  }

  auto phase = [&](int p, int slot) {
    if (role == 0) {
      if (p <= NCHUNK - 1) {                    // chunk m = p
        const int par = p & 1;
        asm volatile("s_waitcnt vmcnt(32)" ::: "memory");
        __builtin_amdgcn_sched_barrier(0);
        float xv[CH];
#pragma unroll
        for (int u = 0; u < CH; ++u) xv[u] = xbuf[grp][slot][u][lane];
        __builtin_amdgcn_sched_barrier(0);
#pragma unroll
        for (int u = 0; u < CH; ++u) {
          float a = cbn;
          a = fmaf(QB(xv[u], 0), wip[0], a);
          a = fmaf(QB(xv[u], 1), wip[1], a);
          a = fmaf(QB(xv[u], 2), wip[2], a);
          a = fmaf(QB(xv[u], 3), wip[3], a);
          iface[grp][0][par][u][lane] = a;
        }
#pragma unroll
        for (int u = 0; u < CH; ++u) {
          int tn = (p + 2) * CH + u;
          if (tn > TSTEPS - 1) tn = TSTEPS - 1; // clamped tail: never read
          xload(&xbuf[grp][(slot+2)%3][u][0], xp + (size_t)tn * STRIDE);
        }
      }
    } else {
      const int m = p - role;                   // source chunk for this wave
      if (m >= 0 && m <= NCHUNK - 1) {
        const int par = m & 1;
        float av[CH];
#pragma unroll
        for (int u = 0; u < CH; ++u) av[u] = iface[grp][role-1][par][u][lane];
        __builtin_amdgcn_sched_barrier(0);
        if (role <= 2) {
          // chain of layer role-1 + DPP-shared ai of layer role (1-delayed)
#pragma unroll
          for (int u = 0; u < CH; ++u) {
            float d0 = QB(r, 0), d1 = QB(r, 1), d2 = QB(r, 2), d3 = QB(r, 3);
            if (u > 0) {                        // ai(u-1) from quad(r_{u-1})
              float a = cbn;
              a = fmaf(d0, wip[0], a);
              a = fmaf(d1, wip[1], a);
              a = fmaf(d2, wip[2], a);
              a = fmaf(d3, wip[3], a);
              iface[grp][role][par][u-1][lane] = a;
            }
            float t0 = fmaf(d0, whp[0], av[u]);
            float t1 = d1 * whp[1];
            t0 = fmaf(d2, whp[2], t0);
            t1 = fmaf(d3, whp[3], t1);
            r = fast_rcp(fast_exp2(t0 + t1) + 1.0f);
          }
          {                                     // epilogue: ai(CH-1)
            float d0 = QB(r, 0), d1 = QB(r, 1), d2 = QB(r, 2), d3 = QB(r, 3);
            float a = cbn;
            a = fmaf(d0, wip[0], a);
            a = fmaf(d1, wip[1], a);
            a = fmaf(d2, wip[2], a);
            a = fmaf(d3, wip[3], a);
            iface[grp][role][par][CH-1][lane] = a;
          }
        } else {
          const int base = m * CH;              // final layer: chain + Y
#pragma unroll
          for (int u = 0; u < CH; ++u) {
            float d0 = QB(r, 0), d1 = QB(r, 1), d2 = QB(r, 2), d3 = QB(r, 3);
            float t0 = fmaf(d0, whp[0], av[u]);
            float t1 = d1 * whp[1];
            t0 = fmaf(d2, whp[2], t0);
            t1 = fmaf(d3, whp[3], t1);
            r = fast_rcp(fast_exp2(t0 + t1) + 1.0f);
            Y[(size_t)(base + u) * STRIDE + g] = fmaf(-2.0f, r, 1.0f);
          }
        }
      }
    }

    // phase boundary: drain LDS ops only (NOT vmcnt), then raw barrier.
    __builtin_amdgcn_sched_barrier(0);
    asm volatile("s_waitcnt lgkmcnt(0)" ::: "memory");
    __builtin_amdgcn_s_barrier();
    __builtin_amdgcn_sched_barrier(0);
  };

  for (int p = 0; p < NPH; p += 3) {   // 69 = 3 * 23, static xbuf slots
    phase(p + 0, 0);
    phase(p + 1, 1);
    phase(p + 2, 2);
  }

  // drain outstanding (clamped-tail) staging loads before LDS dealloc
  if (role == 0) asm volatile("s_waitcnt vmcnt(0)" ::: "memory");
}

extern "C" void kernel_launch(void* const* d_in, const int* in_sizes, int n_in,
                              void* d_out, int out_size, void* d_ws, size_t ws_size,
                              hipStream_t stream) {
  const float* X   = (const float*)d_in[0];
  const float* H0  = (const float*)d_in[1];
  const float* Wih = (const float*)d_in[2];
  const float* Whh = (const float*)d_in[3];
  const float* bih = (const float*)d_in[4];
  const float* bhh = (const float*)d_in[5];
  float* Y = (float*)d_out;

  // 128 blocks x 512 threads: two 4-wave groups per block -> 2 waves/SIMD.
  rnn_pipe8<<<dim3(STRIDE / 128), dim3(512), 0, stream>>>(X, H0, Wih, Whh, bih, bhh, Y);
}

// Round 18
// 143.050 us; speedup vs baseline: 1.1259x; 1.1259x over previous
//
#include <hip/hip_runtime.h>

#define TSTEPS 2048
#define BATCH  4096
#define HID    4
#define STRIDE (BATCH*HID)    // 16384 floats per timestep slab
#define CH     32             // timesteps per chunk (barrier period)
#define NCHUNK (TSTEPS/CH)    // 64 source chunks
#define NPH    69             // >= NCHUNK+5 stages, = 3*23 for slot rotation

// Broadcast component k (0..3) to all 4 lanes of each quad via DPP quad_perm.
#define QB(v,k) __int_as_float(__builtin_amdgcn_update_dpp( \
    0, __float_as_int(v), (k)*0x55, 0xF, 0xF, true))

__device__ __forceinline__ float fast_exp2(float x) {
#if __has_builtin(__builtin_amdgcn_exp2f)
  return __builtin_amdgcn_exp2f(x);
#else
  return exp2f(x);
#endif
}
__device__ __forceinline__ float fast_rcp(float x) {
#if __has_builtin(__builtin_amdgcn_rcpf)
  return __builtin_amdgcn_rcpf(x);
#else
  return 1.0f / x;
#endif
}

// Direct global->LDS 4B load (wave-uniform LDS base + lane*4).
__device__ __forceinline__ void xload(float* ldst, const float* gsrc) {
  __builtin_amdgcn_global_load_lds(
      (const __attribute__((address_space(1))) void*)gsrc,
      (__attribute__((address_space(3))) void*)ldst, 4, 0, 0);
}

// 6-wave chain-purified pipeline (post-mortem r17: in the fused tail, ALL ops
// are downstream of rcp -> serialization. Here chain waves carry ONLY the
// 69-cyc/step chain; ai-production runs on separate waves at full rate.)
//   wave 0 (P) : x staging + ai0 -> aif[0]          (stage 0, chunk m = p)
//   wave 1 (T0): chain L0: r0 seq -> rbuf[0]        (stage 1, m = p-1)
//   wave 2 (A1): ai1 from r0 (prev phase) -> aif[1] (stage 2, m = p-2)
//   wave 3 (T1): chain L1 -> rbuf[1]                (stage 3, m = p-3)
//   wave 4 (A2): ai2 from r1 -> aif[2]              (stage 4, m = p-4)
//   wave 5 (T2): chain L2 -> Y (h = 1-2r)           (stage 5, m = p-5)
// Recurrence on r = 1/(1+exp2(a)), h = 1-2r folded into all weights:
//   T_l: a = av[u] + whp.quad(r),  whp = -2K*Whh[l]
//   P  : ai0 = K*(b0 + Whh0.1) + (K*Wih0).quad(x)
//   A_l: ai_l = K*(b_l + Whh_l.1 + Wih_l.1) + (-2K*Wih_l).quad(r_{l-1})
// Protocol (verified r9/r15): double-buffered LDS by chunk parity, ONE raw
// s_barrier per phase, lgkmcnt(0) drained before it, vmcnt counted (32),
// never drained in-loop. Producer-overwrite happens 2 phases after the
// consumer's read of the same parity slot -> race-free.
__global__ __launch_bounds__(384) void rnn_pipe6(
    const float* __restrict__ X,    // (T, B, H)
    const float* __restrict__ H0,   // (L, B, H)
    const float* __restrict__ Wih,  // (L, H, H)
    const float* __restrict__ Whh,  // (L, H, H)
    const float* __restrict__ bih,  // (L, H)
    const float* __restrict__ bhh,  // (L, H)
    float* __restrict__ Y)          // (T, B, H)
{
  const int lane = threadIdx.x & 63;
  const int w    = threadIdx.x >> 6;            // 0..5 = stage index
  const int g    = blockIdx.x * 64 + lane;      // global (b,j) unit
  const int j    = g & 3;
  const float K  = 2.8853900817779268f;         // 2*log2(e)

  __shared__ float xbuf[3][CH][64];             // 24 KB x staging ring (P)
  __shared__ float aif[3][2][CH][64];           // 48 KB ai handoff -> T_l
  __shared__ float rbuf[2][2][CH][64];          // 32 KB r handoff T_l -> A_l+1

  // Per-wave constants.
  const bool isP = (w == 0);
  const bool isT = (w == 1) || (w == 3) || (w == 5);
  const int  Lt  = (w - 1) >> 1;                // T: layer index (w=1,3,5)
  const int  La  = w >> 1;                      // P/A: ai layer (w=0,2,4)

  float whp[HID], wip[HID], cbn = 0.0f, r = 0.0f;
  if (isT) {
#pragma unroll
    for (int k = 0; k < HID; ++k)
      whp[k] = -2.0f * K * Whh[(Lt*HID + j)*HID + k];
    r = 0.5f * (1.0f - H0[Lt*STRIDE + g]);      // h = 1 - 2r
  } else {
    float wsum = 0.0f;
#pragma unroll
    for (int k = 0; k < HID; ++k) {
      float wik = Wih[(La*HID + j)*HID + k];
      wip[k] = isP ? (K * wik) : (-2.0f * K * wik);
      wsum  += Whh[(La*HID + j)*HID + k] + (isP ? 0.0f : wik);
    }
    cbn = K * (bih[La*HID + j] + bhh[La*HID + j] + wsum);
  }

  const float* __restrict__ xp = X + g;

  // Prime the x pipeline: chunks 0,1 -> slots 0,1 (64 outstanding loads).
  if (isP) {
    __builtin_amdgcn_sched_barrier(0);
    asm volatile("s_waitcnt vmcnt(0)" ::: "memory");  // clean vmcnt baseline
#pragma unroll
    for (int u = 0; u < CH; ++u)
      xload(&xbuf[0][u][0], xp + (size_t)(0*CH + u) * STRIDE);
#pragma unroll
    for (int u = 0; u < CH; ++u)
      xload(&xbuf[1][u][0], xp + (size_t)(1*CH + u) * STRIDE);
  }

  auto phase = [&](int p, int slot) {
    const int m = p - w;                        // this wave's source chunk
    if (m >= 0 && m <= NCHUNK - 1) {            // wave-uniform window
      const int par = m & 1;

      if (isP) {
        // oldest 32 loads (this chunk) have landed in xbuf[slot]
        asm volatile("s_waitcnt vmcnt(32)" ::: "memory");
        __builtin_amdgcn_sched_barrier(0);
        float xv[CH];
#pragma unroll
        for (int u = 0; u < CH; ++u) xv[u] = xbuf[slot][u][lane];
        __builtin_amdgcn_sched_barrier(0);
#pragma unroll
        for (int u = 0; u < CH; ++u) {
          float a = cbn;
          a = fmaf(QB(xv[u], 0), wip[0], a);
          a = fmaf(QB(xv[u], 1), wip[1], a);
          a = fmaf(QB(xv[u], 2), wip[2], a);
          a = fmaf(QB(xv[u], 3), wip[3], a);
          aif[0][par][u][lane] = a;
        }
        // refill: chunk m+2 -> slot (slot+2)%3; always 32 issues (clamped
        // tail loads land but are never consumed -> vmcnt invariant exact)
#pragma unroll
        for (int u = 0; u < CH; ++u) {
          int tn = (m + 2) * CH + u;
          if (tn > TSTEPS - 1) tn = TSTEPS - 1;
          xload(&xbuf[(slot+2)%3][u][0], xp + (size_t)tn * STRIDE);
        }
      } else if (isT) {
        // chain-only wave: batch-hoist ai, then the pure serial chain.
        float av[CH];
#pragma unroll
        for (int u = 0; u < CH; ++u) av[u] = aif[Lt][par][u][lane];
        __builtin_amdgcn_sched_barrier(0);
        if (Lt <= 1) {
#pragma unroll
          for (int u = 0; u < CH; ++u) {
            float t0 = fmaf(QB(r, 0), whp[0], av[u]);
            float t1 =      QB(r, 1) * whp[1];
            t0 = fmaf(QB(r, 2), whp[2], t0);
            t1 = fmaf(QB(r, 3), whp[3], t1);
            r = fast_rcp(fast_exp2(t0 + t1) + 1.0f);
            rbuf[Lt][par][u][lane] = r;         // store off-chain
          }
        } else {
          const int base = m * CH;              // final layer: Y store
#pragma unroll
          for (int u = 0; u < CH; ++u) {
            float t0 = fmaf(QB(r, 0), whp[0], av[u]);
            float t1 =      QB(r, 1) * whp[1];
            t0 = fmaf(QB(r, 2), whp[2], t0);
            t1 = fmaf(QB(r, 3), whp[3], t1);
            r = fast_rcp(fast_exp2(t0 + t1) + 1.0f);
            Y[(size_t)(base + u) * STRIDE + g] = fmaf(-2.0f, r, 1.0f);
          }
        }
      } else {
        // ai-production wave: pure ILP, no chain. Reads r of layer La-1.
        float rv[CH];
#pragma unroll
        for (int u = 0; u < CH; ++u) rv[u] = rbuf[La-1][par][u][lane];
        __builtin_amdgcn_sched_barrier(0);
#pragma unroll
        for (int u = 0; u < CH; ++u) {
          float a = cbn;
          a = fmaf(QB(rv[u], 0), wip[0], a);
          a = fmaf(QB(rv[u], 1), wip[1], a);
          a = fmaf(QB(rv[u], 2), wip[2], a);
          a = fmaf(QB(rv[u], 3), wip[3], a);
          aif[La][par][u][lane] = a;
        }
      }
    }

    // phase boundary: drain LDS ops only (NOT vmcnt), then raw barrier.
    __builtin_amdgcn_sched_barrier(0);
    asm volatile("s_waitcnt lgkmcnt(0)" ::: "memory");
    __builtin_amdgcn_s_barrier();
    __builtin_amdgcn_sched_barrier(0);
  };

  for (int p = 0; p < NPH; p += 3) {   // 69 = 3 * 23, static xbuf slots
    phase(p + 0, 0);
    phase(p + 1, 1);
    phase(p + 2, 2);
  }

  // drain outstanding (clamped-tail) staging loads before LDS dealloc
  if (isP) asm volatile("s_waitcnt vmcnt(0)" ::: "memory");
}

extern "C" void kernel_launch(void* const* d_in, const int* in_sizes, int n_in,
                              void* d_out, int out_size, void* d_ws, size_t ws_size,
                              hipStream_t stream) {
  const float* X   = (const float*)d_in[0];
  const float* H0  = (const float*)d_in[1];
  const float* Wih = (const float*)d_in[2];
  const float* Whh = (const float*)d_in[3];
  const float* bih = (const float*)d_in[4];
  const float* bhh = (const float*)d_in[5];
  float* Y = (float*)d_out;

  // 256 blocks x 384 threads: 6 pipeline-stage waves per CU.
  rnn_pipe6<<<dim3(STRIDE / 64), dim3(384), 0, stream>>>(X, H0, Wih, Whh, bih, bhh, Y);
}